// Round 10
// baseline (393.141 us; speedup 1.0000x reference)
//
#include <hip/hip_runtime.h>
#include <cmath>

// AdaAttnNoConv: b=4, C=512, hw=4096 (fp32 in/out).
// Round 16: revert k_pv to R13 (ring-3 vmcnt(6), verified 111.3us) and add
// per-wave fragment-read pipelining.
// R14/R15 post-mortem: 128x128 ring-2 vmcnt(0) REGRESSED (127us, MfmaUtil
// 45.6, occupancy 18.5 not 40): shortening prefetch to 1 slot exposed HBM
// latency at every boundary; sibling block contended instead of covering.
// R16 k_pv (only change vs R13):
//  - issue ALL 16 frag ds_reads (kk0+kk1) at slot head; lgkmcnt(8) ->
//    kk0 cluster (aal+V^2+32 MFMA); lgkmcnt(0) -> 6 g2l stage -> kk1
//    cluster; vmcnt(6)+barrier. kk1 read latency hides under kk0 MFMA.
//  - barriers, ring-3 staging, swizzle, MFMA order all unchanged ->
//    same absmax (0.1875). +32 VGPR (8 extra f16x8 frags).
// k_qk (R13 BK=64+swizzle, verified), preps, k_red, host tiers unchanged.

#define B_  4
#define C_  512
#define HW_ 4096

typedef _Float16 f16;
typedef _Float16 f16x8 __attribute__((ext_vector_type(8)));
typedef float    f32x4 __attribute__((ext_vector_type(4)));

// Verified gfx950 fragment layouts (learn_hip m89/m91, rounds 1-5 passed):
//  A[m][k]: m = lane&15, k = quad*8 + j
//  B[k][n]: n = lane&15, k = quad*8 + j
//  C/D[m][n]: n = lane&15, m = quad*4 + reg
__device__ __forceinline__ f32x4 mfma16(f16x8 a, f16x8 b, f32x4 c) {
  return __builtin_amdgcn_mfma_f32_16x16x32_f16(a, b, c, 0, 0, 0);
}
__device__ __forceinline__ void g2l16(const f16* g, f16* l) {
  __builtin_amdgcn_global_load_lds(
      (const __attribute__((address_space(1))) void*)g,
      (__attribute__((address_space(3))) void*)l, 16, 0, 0);
}

// ---------------- pass 0: instance-norm stats (mean, rstd) ----------------
__global__ __launch_bounds__(256) void k_stats(
    const float* __restrict__ cx, const float* __restrict__ c1,
    const float* __restrict__ s1,
    float2* __restrict__ cxs, float2* __restrict__ c1s, float2* __restrict__ s1s) {
  int c = blockIdx.x, b = blockIdx.y, t = blockIdx.z;
  const float* src = (t == 0 ? cx : (t == 1 ? c1 : s1)) + (size_t)(b * C_ + c) * HW_;
  float s = 0.f, q = 0.f;
  const float4* src4 = (const float4*)src;
  for (int i = threadIdx.x; i < HW_ / 4; i += 256) {
    float4 v = src4[i];
    s += v.x + v.y + v.z + v.w;
    q += v.x * v.x + v.y * v.y + v.z * v.z + v.w * v.w;
  }
#pragma unroll
  for (int off = 1; off < 64; off <<= 1) {
    s += __shfl_xor(s, off);
    q += __shfl_xor(q, off);
  }
  __shared__ float ss[4], sq[4];
  int wv = threadIdx.x >> 6;
  if ((threadIdx.x & 63) == 0) { ss[wv] = s; sq[wv] = q; }
  __syncthreads();
  if (threadIdx.x == 0) {
    float S = ss[0] + ss[1] + ss[2] + ss[3];
    float Q = sq[0] + sq[1] + sq[2] + sq[3];
    float mean = S * (1.f / HW_);
    float var = Q * (1.f / HW_) - mean * mean;
    float2 r;
    r.x = mean;
    r.y = rsqrtf(var + 1e-5f);
    (t == 0 ? cxs : (t == 1 ? c1s : s1s))[b * C_ + c] = r;
  }
}

// ------- pass 1: normalize + transpose (b,c,p) f32 -> (b,p,c) f16 ---------
__global__ __launch_bounds__(256) void k_prept(
    const float* __restrict__ src, const float2* __restrict__ st,
    f16* __restrict__ dst) {
  int pb = blockIdx.x * 64, cb = blockIdx.y * 64, b = blockIdx.z;
  __shared__ float t[64][65];
  int tj = threadIdx.x & 63, tr = threadIdx.x >> 6;
#pragma unroll 4
  for (int p = 0; p < 16; ++p) {
    int cl = p * 4 + tr;
    float2 mr = st[b * C_ + cb + cl];
    float v = src[(size_t)(b * C_ + cb + cl) * HW_ + pb + tj];
    t[cl][tj] = (v - mr.x) * mr.y;
  }
  __syncthreads();
#pragma unroll 4
  for (int p = 0; p < 16; ++p) {
    int pr = p * 4 + tr;
    dst[(size_t)(b * HW_ + pb + pr) * C_ + cb + tj] = (f16)t[tj][pr];
  }
}

// ---------------- pass 1b: V = s_x -> f16 (same [b][c][k] layout) ---------
__global__ __launch_bounds__(256) void k_prepv(const float* __restrict__ src,
                                               f16* __restrict__ dst) {
  int gid = blockIdx.x * 256 + threadIdx.x;  // over B_*C_*HW_/8
  const float4* s = (const float4*)src + (size_t)gid * 2;
  float4 v0 = s[0], v1 = s[1];
  f16x8 v = {(f16)v0.x, (f16)v0.y, (f16)v0.z, (f16)v0.w,
             (f16)v1.x, (f16)v1.y, (f16)v1.z, (f16)v1.w};
  *(f16x8*)(dst + (size_t)gid * 8) = v;
}

// ------------- pass 2: QK^T GEMM + exp-shifted score store ---------------
// (R13, verified: BK=64 ring-2, full swizzle, conflict-free reads)
__global__ __launch_bounds__(512, 2) void k_qk(
    const f16* __restrict__ Qt, const f16* __restrict__ Kt,
    f16* __restrict__ E, float2* __restrict__ mlpart,
    int qspan, int qt256, int npair) {
  int id = blockIdx.x, pair, kt;
  if ((npair & 7) == 0) {
    int xcd = id & 7, j = id >> 3, qrs = npair >> 3;
    pair = xcd * qrs + (j % qrs);
    kt = j / qrs;
  } else {
    pair = id >> 4;
    kt = id & 15;
  }
  int bz = pair / qt256, qt = pair - bz * qt256;

  const f16* Aq = Qt + ((size_t)(bz * qspan + qt * 256)) * C_;
  const f16* Bk = Kt + (size_t)bz * HW_ * C_ + (size_t)kt * 256 * C_;
  f16* Eb = E + ((size_t)(bz * qspan + qt * 256)) * HW_ + kt * 256;
  float2* mlb = mlpart + ((size_t)(bz * qspan + qt * 256)) * 16 + kt;

  // ring-2 of (A 256x64 + B 256x64) f16 = 2x32768; ebuf overlays ring
  __shared__ __align__(16) union ShQK {
    f16 ring[2 * 32768];
    f16 ebuf[64 * 272];
  } sh;
  __shared__ float sred[2][256];

  int t = threadIdx.x, wave = t >> 6, lane = t & 63, lq = lane & 15, quad = lane >> 4;
  int wy = wave >> 1, wx = wave & 1;

  // staging: thread t covers (row = t>>3 in 64-row chunk, swizzled 16B chunk)
  int srow = t >> 3;
  int scol = ((t & 7) ^ (srow & 7)) * 8;  // pre-swizzled source col (f16)

  // fragment read offsets (f16, within slot buffer); +mt*1024 / +nt*1024
  int aoff = (wy * 64 + lq) * 64;
  int boff = 16384 + (wx * 128 + lq) * 64;
  int cx0 = (quad * 8) ^ ((lq & 7) << 3);        // kk=0 chunk, swizzled
  int cx1 = (32 + quad * 8) ^ ((lq & 7) << 3);   // kk=1 chunk, swizzled

  f32x4 acc[4][8];
#pragma unroll
  for (int mt = 0; mt < 4; ++mt)
#pragma unroll
    for (int nt = 0; nt < 8; ++nt) acc[mt][nt] = (f32x4){0, 0, 0, 0};

  // ---- prologue: stage slot 0 (8 g2l) ----
#pragma unroll
  for (int i = 0; i < 4; ++i)
    g2l16(Aq + (size_t)(i * 64 + srow) * C_ + scol, sh.ring + i * 4096 + t * 8);
#pragma unroll
  for (int i = 0; i < 4; ++i)
    g2l16(Bk + (size_t)(i * 64 + srow) * C_ + scol, sh.ring + 16384 + i * 4096 + t * 8);
  asm volatile("s_waitcnt vmcnt(0)" ::: "memory");
  __builtin_amdgcn_s_barrier();

  // ---- main loop: 8 slots, ring-2 ----
  int cur = 0;
  for (int s = 0; s < 8; ++s) {
    const f16* base = sh.ring + cur * 32768;
    int nxOff = (cur ^ 1) * 32768;
    bool st = s < 7;
    int c1g = (s + 1) * 64;

    f16x8 af[4], bf[8];
    // ---- phase kk=0 ----
#pragma unroll
    for (int mt = 0; mt < 4; ++mt)
      af[mt] = *(const f16x8*)(base + aoff + mt * 1024 + cx0);
#pragma unroll
    for (int nt = 0; nt < 8; ++nt)
      bf[nt] = *(const f16x8*)(base + boff + nt * 1024 + cx0);
    if (st) {
#pragma unroll
      for (int i = 0; i < 4; ++i)
        g2l16(Aq + (size_t)(i * 64 + srow) * C_ + c1g + scol,
              sh.ring + nxOff + i * 4096 + t * 8);
    }
    asm volatile("s_waitcnt lgkmcnt(0)" ::: "memory");
    __builtin_amdgcn_sched_barrier(0);
    __builtin_amdgcn_s_setprio(1);
#pragma unroll
    for (int mt = 0; mt < 4; ++mt)
#pragma unroll
      for (int nt = 0; nt < 8; ++nt)
        acc[mt][nt] = mfma16(af[mt], bf[nt], acc[mt][nt]);
    __builtin_amdgcn_s_setprio(0);

    // ---- phase kk=1 ----
#pragma unroll
    for (int mt = 0; mt < 4; ++mt)
      af[mt] = *(const f16x8*)(base + aoff + mt * 1024 + cx1);
#pragma unroll
    for (int nt = 0; nt < 8; ++nt)
      bf[nt] = *(const f16x8*)(base + boff + nt * 1024 + cx1);
    if (st) {
#pragma unroll
      for (int i = 0; i < 4; ++i)
        g2l16(Bk + (size_t)(i * 64 + srow) * C_ + c1g + scol,
              sh.ring + nxOff + 16384 + i * 4096 + t * 8);
    }
    asm volatile("s_waitcnt lgkmcnt(0)" ::: "memory");
    __builtin_amdgcn_sched_barrier(0);
    __builtin_amdgcn_s_setprio(1);
#pragma unroll
    for (int mt = 0; mt < 4; ++mt)
#pragma unroll
      for (int nt = 0; nt < 8; ++nt)
        acc[mt][nt] = mfma16(af[mt], bf[nt], acc[mt][nt]);
    __builtin_amdgcn_s_setprio(0);

    asm volatile("s_waitcnt vmcnt(0)" ::: "memory");
    __builtin_amdgcn_s_barrier();
    cur ^= 1;
  }

  // ---- tile row max (merge wx halves through sred) ----
#pragma unroll
  for (int mt = 0; mt < 4; ++mt)
#pragma unroll
    for (int r = 0; r < 4; ++r) {
      float v = -1e30f;
#pragma unroll
      for (int nt = 0; nt < 8; ++nt) v = fmaxf(v, acc[mt][nt][r]);
#pragma unroll
      for (int msk = 1; msk < 16; msk <<= 1) v = fmaxf(v, __shfl_xor(v, msk));
      if (lq == 0) sred[wx][wy * 64 + mt * 16 + quad * 4 + r] = v;
    }
  __syncthreads();
  float mrow[4][4];
#pragma unroll
  for (int mt = 0; mt < 4; ++mt)
#pragma unroll
    for (int r = 0; r < 4; ++r) {
      int rr = wy * 64 + mt * 16 + quad * 4 + r;
      mrow[mt][r] = fmaxf(sred[0][rr], sred[1][rr]);
    }

  // ---- E = exp(s - m_t): XOR-swizzled ebuf transpose -> 16B stores ----
  float rsum[4][4];
#pragma unroll
  for (int mt = 0; mt < 4; ++mt)
#pragma unroll
    for (int r = 0; r < 4; ++r) rsum[mt][r] = 0.f;

#pragma unroll
  for (int mt = 0; mt < 4; ++mt) {
    __syncthreads();  // prev phase's ebuf reads done (mt=0: K-loop/sred done)
#pragma unroll
    for (int nt = 0; nt < 8; ++nt) {
      f32x4 v = acc[mt][nt];
      // chunk = col>>3; swizzled chunk = chunk ^ (quad<<1)
      int cs = ((wx * 16 + nt * 2 + (lq >> 3)) ^ (quad << 1)) * 8 + (lq & 7);
#pragma unroll
      for (int r = 0; r < 4; ++r) {
        float e = __expf(v[r] - mrow[mt][r]);
        rsum[mt][r] += e;
        sh.ebuf[(wy * 16 + quad * 4 + r) * 272 + cs] = (f16)e;
      }
    }
    __syncthreads();  // ebuf visible
#pragma unroll
    for (int i = 0; i < 4; ++i) {
      int idx = i * 512 + t;
      int rl = idx >> 5, ck = idx & 31;
      int cr = (ck ^ (((rl >> 2) & 3) << 1)) * 8;
      f16x8 v8 = *(const f16x8*)(sh.ebuf + rl * 272 + cr);
      int grow = (rl >> 4) * 64 + mt * 16 + (rl & 15);
      *(f16x8*)(Eb + (size_t)grow * HW_ + ck * 8) = v8;
    }
  }

  // ---- row-sum partials -> mlpart ----
#pragma unroll
  for (int mt = 0; mt < 4; ++mt)
#pragma unroll
    for (int r = 0; r < 4; ++r) {
      float v = rsum[mt][r];
#pragma unroll
      for (int msk = 1; msk < 16; msk <<= 1) v += __shfl_xor(v, msk);
      if (lq == 0) sred[wx][wy * 64 + mt * 16 + quad * 4 + r] = v;
    }
  __syncthreads();
  if (wx == 0 && lq == 0) {
#pragma unroll
    for (int mt = 0; mt < 4; ++mt)
#pragma unroll
      for (int r = 0; r < 4; ++r) {
        int rr = wy * 64 + mt * 16 + quad * 4 + r;
        mlb[(size_t)rr * 16] = make_float2(mrow[mt][r], sred[0][rr] + sred[1][rr]);
      }
  }
}

// ---- pass 3: exact softmax merge -> alpha[row][kt16] = exp(m_t-m)/l ------
__global__ __launch_bounds__(256) void k_red(const float2* __restrict__ mlpart,
                                             float* __restrict__ alpha) {
  int row = blockIdx.x * 256 + threadIdx.x;
  const float2* p = mlpart + (size_t)row * 16;
  float2 loc[16];
  float m = -1e30f;
#pragma unroll
  for (int i = 0; i < 16; ++i) {
    loc[i] = p[i];
    m = fmaxf(m, loc[i].x);
  }
  float l = 0.f;
#pragma unroll
  for (int i = 0; i < 16; ++i) l += loc[i].y * __expf(loc[i].x - m);
  float invl = 1.f / l;
#pragma unroll
  for (int i = 0; i < 16; ++i)
    alpha[(size_t)row * 16 + i] = __expf(loc[i].x - m) * invl;
}

// ------ pass 4: (E*alpha) x V, ring-3 (R13) + frag-read pipelining -------
// 256q x 128ch, 8 waves, BK=64, 64 slots, ring-3, vmcnt(6) boundary.
// Per slot: issue aal + ALL 16 frag b128 -> lgkmcnt(8) -> kk0 cluster ->
// lgkmcnt(0) -> 6 g2l stage -> kk1 cluster -> vmcnt(6) -> barrier.
#define PV_STAGE_A(i)                                                         \
  g2l16(Ap + (size_t)((i)*64 + srow) * HW_ + s2 * 64 + scol,                  \
        sm + pnOff + (i)*4096 + t * 8)
#define PV_STAGE_B(i)                                                         \
  g2l16(Bv + (size_t)((i)*64 + srow) * HW_ + s2 * 64 + scol,                  \
        sm + pnOff + 16384 + (i)*4096 + t * 8)

// 32-MFMA cluster, order identical to R13's PV_PHASE (mt-major, M/M2 pairs)
#define PV_CLUSTER(A0, A1, A2, A3, B0, B1, B2, B3)                            \
  {                                                                           \
    f16x8 q0 = (B0)*(B0), q1 = (B1)*(B1), q2 = (B2)*(B2), q3 = (B3)*(B3);     \
    accM [0][0] = mfma16(A0, B0, accM [0][0]);                                \
    accM2[0][0] = mfma16(A0, q0, accM2[0][0]);                                \
    accM [0][1] = mfma16(A0, B1, accM [0][1]);                                \
    accM2[0][1] = mfma16(A0, q1, accM2[0][1]);                                \
    accM [0][2] = mfma16(A0, B2, accM [0][2]);                                \
    accM2[0][2] = mfma16(A0, q2, accM2[0][2]);                                \
    accM [0][3] = mfma16(A0, B3, accM [0][3]);                                \
    accM2[0][3] = mfma16(A0, q3, accM2[0][3]);                                \
    accM [1][0] = mfma16(A1, B0, accM [1][0]);                                \
    accM2[1][0] = mfma16(A1, q0, accM2[1][0]);                                \
    accM [1][1] = mfma16(A1, B1, accM [1][1]);                                \
    accM2[1][1] = mfma16(A1, q1, accM2[1][1]);                                \
    accM [1][2] = mfma16(A1, B2, accM [1][2]);                                \
    accM2[1][2] = mfma16(A1, q2, accM2[1][2]);                                \
    accM [1][3] = mfma16(A1, B3, accM [1][3]);                                \
    accM2[1][3] = mfma16(A1, q3, accM2[1][3]);                                \
    accM [2][0] = mfma16(A2, B0, accM [2][0]);                                \
    accM2[2][0] = mfma16(A2, q0, accM2[2][0]);                                \
    accM [2][1] = mfma16(A2, B1, accM [2][1]);                                \
    accM2[2][1] = mfma16(A2, q1, accM2[2][1]);                                \
    accM [2][2] = mfma16(A2, B2, accM [2][2]);                                \
    accM2[2][2] = mfma16(A2, q2, accM2[2][2]);                                \
    accM [2][3] = mfma16(A2, B3, accM [2][3]);                                \
    accM2[2][3] = mfma16(A2, q3, accM2[2][3]);                                \
    accM [3][0] = mfma16(A3, B0, accM [3][0]);                                \
    accM2[3][0] = mfma16(A3, q0, accM2[3][0]);                                \
    accM [3][1] = mfma16(A3, B1, accM [3][1]);                                \
    accM2[3][1] = mfma16(A3, q1, accM2[3][1]);                                \
    accM [3][2] = mfma16(A3, B2, accM [3][2]);                                \
    accM2[3][2] = mfma16(A3, q2, accM2[3][2]);                                \
    accM [3][3] = mfma16(A3, B3, accM [3][3]);                                \
    accM2[3][3] = mfma16(A3, q3, accM2[3][3]);                                \
  }

__global__ __launch_bounds__(512, 2) void k_pv(
    const f16* __restrict__ P, const float* __restrict__ alphaG,
    const f16* __restrict__ V, const float* __restrict__ cx,
    const float2* __restrict__ cxs, float* __restrict__ out,
    int qspan, int qbase, int qt256) {
  int npairs = (int)gridDim.x >> 2;
  int id = blockIdx.x, pair, ct;
  if ((npairs & 7) == 0) {
    int x = id & 7, j = id >> 3, ppx = npairs >> 3;
    pair = x * ppx + (j >> 2);
    ct = j & 3;
  } else {
    pair = id >> 2;
    ct = id & 3;
  }
  int bz = pair / qt256, qt = pair - bz * qt256;

  const f16* Ap = P + ((size_t)(bz * qspan + qt * 256)) * HW_;
  const f16* Bv = V + ((size_t)(bz * C_ + ct * 128)) * HW_;

  // LDS: 3 slots x (A 256x64 + B 128x64 f16 = 24576 f16) + alpha f16[256][17]
  __shared__ __align__(16) f16 sm[3 * 24576 + 256 * 17];
  f16* Alh = sm + 3 * 24576;

  int t = threadIdx.x, wave = t >> 6, lane = t & 63, lq = lane & 15, quad = lane >> 4;
  int wy = wave >> 1, wx = wave & 1;

  // ---- stage alpha as f16 (cast f32->f16 at use in baseline: identical) --
  {
    const float* ag = alphaG + ((size_t)(bz * qspan + qt * 256)) * 16;
#pragma unroll
    for (int i = 0; i < 8; ++i) {
      int e = i * 512 + t;
      Alh[(e >> 4) * 17 + (e & 15)] = (f16)ag[e];
    }
  }

  // staging map: thread t covers (row = t>>3 within 64-row chunk, 16B chunk)
  int srow = t >> 3;
  int scol = ((t & 7) ^ (srow & 7)) * 8;  // pre-swizzled source col (f16)

  // fragment read offsets (f16 units, within slot)
  int aoff = (wy * 64 + lq) * 64;
  int boff = (wx * 64 + lq) * 64;
  int cx0 = (quad * 8) ^ ((lq & 7) << 3);        // kk=0, swizzled
  int cx1 = (32 + quad * 8) ^ ((lq & 7) << 3);   // kk=1, swizzled

  f32x4 accM[4][4], accM2[4][4];
#pragma unroll
  for (int mt = 0; mt < 4; ++mt)
#pragma unroll
    for (int nt = 0; nt < 4; ++nt) {
      accM[mt][nt] = (f32x4){0, 0, 0, 0};
      accM2[mt][nt] = (f32x4){0, 0, 0, 0};
    }

  // ---- prologue: stage slots 0,1 (6 loads each) ----
#pragma unroll
  for (int s0 = 0; s0 < 2; ++s0) {
    int off = s0 * 24576;
#pragma unroll
    for (int i = 0; i < 4; ++i)
      g2l16(Ap + (size_t)(i * 64 + srow) * HW_ + s0 * 64 + scol,
            sm + off + i * 4096 + t * 8);
#pragma unroll
    for (int i = 0; i < 2; ++i)
      g2l16(Bv + (size_t)(i * 64 + srow) * HW_ + s0 * 64 + scol,
            sm + off + 16384 + i * 4096 + t * 8);
  }
  asm volatile("s_waitcnt lgkmcnt(0)" ::: "memory");  // alpha ds_writes drained
  asm volatile("s_waitcnt vmcnt(6)" ::: "memory");    // slot 0 landed
  __builtin_amdgcn_s_barrier();

  // ---- main loop: 64 slots, ring-3, one barrier per slot ----
  int ph = 0, pn = 2;
  for (int s = 0; s < 64; ++s) {
    const f16* As_s = sm + ph * 24576;
    const f16* Bs_s = As_s + 16384;
    int pnOff = pn * 24576;
    int s2 = s + 2;
    bool st = s < 62;
    int ktl = s >> 2;  // 256-key alpha tile index
    f16 aal0 = Alh[(wy * 64 + lq +  0) * 17 + ktl];
    f16 aal1 = Alh[(wy * 64 + lq + 16) * 17 + ktl];
    f16 aal2 = Alh[(wy * 64 + lq + 32) * 17 + ktl];
    f16 aal3 = Alh[(wy * 64 + lq + 48) * 17 + ktl];

    // issue ALL fragment reads for both kk phases (16 x ds_read_b128)
    f16x8 a00 = *(const f16x8*)(As_s + aoff + 0 * 1024 + cx0);
    f16x8 a01 = *(const f16x8*)(As_s + aoff + 1 * 1024 + cx0);
    f16x8 a02 = *(const f16x8*)(As_s + aoff + 2 * 1024 + cx0);
    f16x8 a03 = *(const f16x8*)(As_s + aoff + 3 * 1024 + cx0);
    f16x8 b00 = *(const f16x8*)(Bs_s + boff + 0 * 1024 + cx0);
    f16x8 b01 = *(const f16x8*)(Bs_s + boff + 1 * 1024 + cx0);
    f16x8 b02 = *(const f16x8*)(Bs_s + boff + 2 * 1024 + cx0);
    f16x8 b03 = *(const f16x8*)(Bs_s + boff + 3 * 1024 + cx0);
    f16x8 a10 = *(const f16x8*)(As_s + aoff + 0 * 1024 + cx1);
    f16x8 a11 = *(const f16x8*)(As_s + aoff + 1 * 1024 + cx1);
    f16x8 a12 = *(const f16x8*)(As_s + aoff + 2 * 1024 + cx1);
    f16x8 a13 = *(const f16x8*)(As_s + aoff + 3 * 1024 + cx1);
    f16x8 b10 = *(const f16x8*)(Bs_s + boff + 0 * 1024 + cx1);
    f16x8 b11 = *(const f16x8*)(Bs_s + boff + 1 * 1024 + cx1);
    f16x8 b12 = *(const f16x8*)(Bs_s + boff + 2 * 1024 + cx1);
    f16x8 b13 = *(const f16x8*)(Bs_s + boff + 3 * 1024 + cx1);

    asm volatile("s_waitcnt lgkmcnt(8)" ::: "memory");  // aal + kk0 landed
    __builtin_amdgcn_sched_barrier(0);
    __builtin_amdgcn_s_setprio(1);
    a00 *= aal0; a01 *= aal1; a02 *= aal2; a03 *= aal3;
    PV_CLUSTER(a00, a01, a02, a03, b00, b01, b02, b03)
    __builtin_amdgcn_s_setprio(0);

    asm volatile("s_waitcnt lgkmcnt(0)" ::: "memory");  // kk1 landed
    __builtin_amdgcn_sched_barrier(0);
    if (st) {
      PV_STAGE_A(0); PV_STAGE_A(1); PV_STAGE_A(2); PV_STAGE_A(3);
      PV_STAGE_B(0); PV_STAGE_B(1);
    }
    __builtin_amdgcn_s_setprio(1);
    a10 *= aal0; a11 *= aal1; a12 *= aal2; a13 *= aal3;
    PV_CLUSTER(a10, a11, a12, a13, b10, b11, b12, b13)
    __builtin_amdgcn_s_setprio(0);

    if (st) { asm volatile("s_waitcnt vmcnt(6)" ::: "memory"); }
    else    { asm volatile("s_waitcnt vmcnt(0)" ::: "memory"); }
    __builtin_amdgcn_s_barrier();

    ph = (ph == 2) ? 0 : ph + 1;
    pn = (pn == 2) ? 0 : pn + 1;
  }

  // ---- epilogue: fused sqrt(clip(M2-M^2))*IN(c_x)+M, all lanes ----
  int chbase = ct * 128 + wx * 64;
#pragma unroll
  for (int mt = 0; mt < 4; ++mt) {
    int q0 = qbase + qt * 256 + wy * 64 + mt * 16 + quad * 4;
#pragma unroll
    for (int nt = 0; nt < 4; ++nt) {
      int c = chbase + nt * 16 + lq;
      float2 stc = cxs[bz * C_ + c];
      size_t base = ((size_t)bz * C_ + c) * HW_ + q0;
      float4 cv = *(const float4*)(cx + base);
      f32x4 m1 = accM[mt][nt], m2 = accM2[mt][nt];
      float4 o;
      o.x = sqrtf(fmaxf(m2[0] - m1[0] * m1[0], 1e-6f)) * ((cv.x - stc.x) * stc.y) + m1[0];
      o.y = sqrtf(fmaxf(m2[1] - m1[1] * m1[1], 1e-6f)) * ((cv.y - stc.x) * stc.y) + m1[1];
      o.z = sqrtf(fmaxf(m2[2] - m1[2] * m1[2], 1e-6f)) * ((cv.z - stc.x) * stc.y) + m1[2];
      o.w = sqrtf(fmaxf(m2[3] - m1[3] * m1[3], 1e-6f)) * ((cv.w - stc.x) * stc.y) + m1[3];
      *(float4*)(out + base) = o;
    }
  }
}

// --------------------------------- host -----------------------------------
extern "C" void kernel_launch(void* const* d_in, const int* in_sizes, int n_in,
                              void* d_out, int out_size, void* d_ws,
                              size_t ws_size, hipStream_t stream) {
  const float* c_x = (const float*)d_in[0];
  const float* s_x = (const float*)d_in[1];
  const float* c1x = (const float*)d_in[2];
  const float* s1x = (const float*)d_in[3];
  float* out = (float*)d_out;

  char* ws = (char*)d_ws;
  size_t o = 0;
  f16* Qt = (f16*)(ws + o);  o += (size_t)B_ * HW_ * C_ * 2;        // 16 MiB
  f16* Kt = (f16*)(ws + o);  o += (size_t)B_ * HW_ * C_ * 2;        // 16 MiB
  f16* Vh = (f16*)(ws + o);  o += (size_t)B_ * HW_ * C_ * 2;        // 16 MiB
  float2* cxs = (float2*)(ws + o); o += B_ * C_ * sizeof(float2);
  float2* c1s = (float2*)(ws + o); o += B_ * C_ * sizeof(float2);
  float2* s1s = (float2*)(ws + o); o += B_ * C_ * sizeof(float2);
  size_t fixed = (o + 255) & ~(size_t)255;

  // score-region tiers: rows = nb*qspan; bytes/row = E + mlpart + alpha(f32)
  const size_t per_row = (size_t)HW_ * 2 + 16 * 8 + 16 * 4;
  struct Cfg { int nb, qs; };
  const Cfg cfgs[5] = {{4, 4096}, {1, 4096}, {1, 2048}, {1, 1024}, {1, 512}};
  Cfg cfg = cfgs[4];
  for (int i = 0; i < 5; ++i) {
    size_t rows = (size_t)cfgs[i].nb * cfgs[i].qs;
    if (fixed + rows * per_row <= ws_size) { cfg = cfgs[i]; break; }
  }
  const int nb = cfg.nb, qspan = cfg.qs, qt256 = qspan / 256;
  const int npair256 = nb * qt256;
  const size_t rows = (size_t)nb * qspan;
  f16* E = (f16*)(ws + fixed);
  float2* mlpart = (float2*)(ws + fixed + rows * HW_ * 2);
  float* alpha = (float*)(ws + fixed + rows * HW_ * 2 + rows * 16 * 8);

  k_stats<<<dim3(C_, B_, 3), 256, 0, stream>>>(c_x, c1x, s1x, cxs, c1s, s1s);
  k_prept<<<dim3(HW_ / 64, C_ / 64, B_), 256, 0, stream>>>(c1x, c1s, Qt);
  k_prept<<<dim3(HW_ / 64, C_ / 64, B_), 256, 0, stream>>>(s1x, s1s, Kt);
  k_prepv<<<dim3(B_ * C_ * HW_ / 8 / 256), 256, 0, stream>>>(s_x, Vh);

  for (int b0 = 0; b0 < B_; b0 += nb) {
    for (int qb = 0; qb < HW_; qb += qspan) {
      const f16* Qtp = Qt + ((size_t)b0 * HW_ + qb) * C_;
      const f16* Ktp = Kt + (size_t)b0 * HW_ * C_;
      const f16* Vp = Vh + (size_t)b0 * C_ * HW_;
      const float* cxp = c_x + (size_t)b0 * C_ * HW_;
      const float2* cxsp = cxs + b0 * C_;
      float* outp = out + (size_t)b0 * C_ * HW_;

      k_qk<<<dim3((unsigned)(npair256 * 16)), 512, 0, stream>>>(
          Qtp, Ktp, E, mlpart, qspan, qt256, npair256);
      k_red<<<dim3((unsigned)(rows / 256)), 256, 0, stream>>>(mlpart, alpha);
      k_pv<<<dim3((unsigned)(npair256 * 4)), 512, 0, stream>>>(
          E, alpha, Vp, cxp, cxsp, outp, qspan, qb, qt256);
    }
  }
}

// Round 11
// 386.260 us; speedup vs baseline: 1.0178x; 1.0178x over previous
//
#include <hip/hip_runtime.h>
#include <cmath>

// AdaAttnNoConv: b=4, C=512, hw=4096 (fp32 in/out).
// Round 17: strip intra-slot lgkmcnt(0)+sched_barrier(0) from k_qk & k_pv.
// R16 post-mortem: batched frag reads + lgkmcnt(8) REGRESSED (116.3 vs
// R13's 111.3, MfmaUtil 48.6 vs 50.5). LDS pipe (~2300cyc/slot/CU) and
// MFMA pipe (~2480) are co-critical; my explicit lgkmcnt(0)+SB pairs force
// drain-then-compute (the documented m141 anti-pattern) and block the
// compiler's fine-grained lgkmcnt(N) interleave (m97 evidence).
// R17 = R13 k_qk + R13 k_pv with ONLY the intra-slot waits removed:
//  - compiler now inserts minimal lgkm waits between ds_read and MFMA;
//    reads/MFMAs interleave. Boundary vmcnt+barrier, prologue drains,
//    setprio, swizzles, staging placement, MFMA order ALL unchanged.
//  - per-element accumulation chains identical -> same absmax (0.1875).
//  - safety: every ds_read feeds an MFMA before the boundary barrier, so
//    lgkm is drained before any buffer reuse; no new races.

#define B_  4
#define C_  512
#define HW_ 4096

typedef _Float16 f16;
typedef _Float16 f16x8 __attribute__((ext_vector_type(8)));
typedef float    f32x4 __attribute__((ext_vector_type(4)));

// Verified gfx950 fragment layouts (learn_hip m89/m91, rounds 1-5 passed):
//  A[m][k]: m = lane&15, k = quad*8 + j
//  B[k][n]: n = lane&15, k = quad*8 + j
//  C/D[m][n]: n = lane&15, m = quad*4 + reg
__device__ __forceinline__ f32x4 mfma16(f16x8 a, f16x8 b, f32x4 c) {
  return __builtin_amdgcn_mfma_f32_16x16x32_f16(a, b, c, 0, 0, 0);
}
__device__ __forceinline__ void g2l16(const f16* g, f16* l) {
  __builtin_amdgcn_global_load_lds(
      (const __attribute__((address_space(1))) void*)g,
      (__attribute__((address_space(3))) void*)l, 16, 0, 0);
}

// ---------------- pass 0: instance-norm stats (mean, rstd) ----------------
__global__ __launch_bounds__(256) void k_stats(
    const float* __restrict__ cx, const float* __restrict__ c1,
    const float* __restrict__ s1,
    float2* __restrict__ cxs, float2* __restrict__ c1s, float2* __restrict__ s1s) {
  int c = blockIdx.x, b = blockIdx.y, t = blockIdx.z;
  const float* src = (t == 0 ? cx : (t == 1 ? c1 : s1)) + (size_t)(b * C_ + c) * HW_;
  float s = 0.f, q = 0.f;
  const float4* src4 = (const float4*)src;
  for (int i = threadIdx.x; i < HW_ / 4; i += 256) {
    float4 v = src4[i];
    s += v.x + v.y + v.z + v.w;
    q += v.x * v.x + v.y * v.y + v.z * v.z + v.w * v.w;
  }
#pragma unroll
  for (int off = 1; off < 64; off <<= 1) {
    s += __shfl_xor(s, off);
    q += __shfl_xor(q, off);
  }
  __shared__ float ss[4], sq[4];
  int wv = threadIdx.x >> 6;
  if ((threadIdx.x & 63) == 0) { ss[wv] = s; sq[wv] = q; }
  __syncthreads();
  if (threadIdx.x == 0) {
    float S = ss[0] + ss[1] + ss[2] + ss[3];
    float Q = sq[0] + sq[1] + sq[2] + sq[3];
    float mean = S * (1.f / HW_);
    float var = Q * (1.f / HW_) - mean * mean;
    float2 r;
    r.x = mean;
    r.y = rsqrtf(var + 1e-5f);
    (t == 0 ? cxs : (t == 1 ? c1s : s1s))[b * C_ + c] = r;
  }
}

// ------- pass 1: normalize + transpose (b,c,p) f32 -> (b,p,c) f16 ---------
__global__ __launch_bounds__(256) void k_prept(
    const float* __restrict__ src, const float2* __restrict__ st,
    f16* __restrict__ dst) {
  int pb = blockIdx.x * 64, cb = blockIdx.y * 64, b = blockIdx.z;
  __shared__ float t[64][65];
  int tj = threadIdx.x & 63, tr = threadIdx.x >> 6;
#pragma unroll 4
  for (int p = 0; p < 16; ++p) {
    int cl = p * 4 + tr;
    float2 mr = st[b * C_ + cb + cl];
    float v = src[(size_t)(b * C_ + cb + cl) * HW_ + pb + tj];
    t[cl][tj] = (v - mr.x) * mr.y;
  }
  __syncthreads();
#pragma unroll 4
  for (int p = 0; p < 16; ++p) {
    int pr = p * 4 + tr;
    dst[(size_t)(b * HW_ + pb + pr) * C_ + cb + tj] = (f16)t[tj][pr];
  }
}

// ---------------- pass 1b: V = s_x -> f16 (same [b][c][k] layout) ---------
__global__ __launch_bounds__(256) void k_prepv(const float* __restrict__ src,
                                               f16* __restrict__ dst) {
  int gid = blockIdx.x * 256 + threadIdx.x;  // over B_*C_*HW_/8
  const float4* s = (const float4*)src + (size_t)gid * 2;
  float4 v0 = s[0], v1 = s[1];
  f16x8 v = {(f16)v0.x, (f16)v0.y, (f16)v0.z, (f16)v0.w,
             (f16)v1.x, (f16)v1.y, (f16)v1.z, (f16)v1.w};
  *(f16x8*)(dst + (size_t)gid * 8) = v;
}

// ------------- pass 2: QK^T GEMM + exp-shifted score store ---------------
// R13 structure (BK=64 ring-2, full swizzle); intra-slot waits removed —
// compiler schedules ds_read<->MFMA interleave.
__global__ __launch_bounds__(512, 2) void k_qk(
    const f16* __restrict__ Qt, const f16* __restrict__ Kt,
    f16* __restrict__ E, float2* __restrict__ mlpart,
    int qspan, int qt256, int npair) {
  int id = blockIdx.x, pair, kt;
  if ((npair & 7) == 0) {
    int xcd = id & 7, j = id >> 3, qrs = npair >> 3;
    pair = xcd * qrs + (j % qrs);
    kt = j / qrs;
  } else {
    pair = id >> 4;
    kt = id & 15;
  }
  int bz = pair / qt256, qt = pair - bz * qt256;

  const f16* Aq = Qt + ((size_t)(bz * qspan + qt * 256)) * C_;
  const f16* Bk = Kt + (size_t)bz * HW_ * C_ + (size_t)kt * 256 * C_;
  f16* Eb = E + ((size_t)(bz * qspan + qt * 256)) * HW_ + kt * 256;
  float2* mlb = mlpart + ((size_t)(bz * qspan + qt * 256)) * 16 + kt;

  // ring-2 of (A 256x64 + B 256x64) f16 = 2x32768; ebuf overlays ring
  __shared__ __align__(16) union ShQK {
    f16 ring[2 * 32768];
    f16 ebuf[64 * 272];
  } sh;
  __shared__ float sred[2][256];

  int t = threadIdx.x, wave = t >> 6, lane = t & 63, lq = lane & 15, quad = lane >> 4;
  int wy = wave >> 1, wx = wave & 1;

  // staging: thread t covers (row = t>>3 in 64-row chunk, swizzled 16B chunk)
  int srow = t >> 3;
  int scol = ((t & 7) ^ (srow & 7)) * 8;  // pre-swizzled source col (f16)

  // fragment read offsets (f16, within slot buffer); +mt*1024 / +nt*1024
  int aoff = (wy * 64 + lq) * 64;
  int boff = 16384 + (wx * 128 + lq) * 64;
  int cx0 = (quad * 8) ^ ((lq & 7) << 3);        // kk=0 chunk, swizzled
  int cx1 = (32 + quad * 8) ^ ((lq & 7) << 3);   // kk=1 chunk, swizzled

  f32x4 acc[4][8];
#pragma unroll
  for (int mt = 0; mt < 4; ++mt)
#pragma unroll
    for (int nt = 0; nt < 8; ++nt) acc[mt][nt] = (f32x4){0, 0, 0, 0};

  // ---- prologue: stage slot 0 (8 g2l) ----
#pragma unroll
  for (int i = 0; i < 4; ++i)
    g2l16(Aq + (size_t)(i * 64 + srow) * C_ + scol, sh.ring + i * 4096 + t * 8);
#pragma unroll
  for (int i = 0; i < 4; ++i)
    g2l16(Bk + (size_t)(i * 64 + srow) * C_ + scol, sh.ring + 16384 + i * 4096 + t * 8);
  asm volatile("s_waitcnt vmcnt(0)" ::: "memory");
  __builtin_amdgcn_s_barrier();

  // ---- main loop: 8 slots, ring-2 ----
  int cur = 0;
  for (int s = 0; s < 8; ++s) {
    const f16* base = sh.ring + cur * 32768;
    int nxOff = (cur ^ 1) * 32768;
    bool st = s < 7;
    int c1g = (s + 1) * 64;

    f16x8 af[4], bf[8];
    // ---- phase kk=0 ----
#pragma unroll
    for (int mt = 0; mt < 4; ++mt)
      af[mt] = *(const f16x8*)(base + aoff + mt * 1024 + cx0);
#pragma unroll
    for (int nt = 0; nt < 8; ++nt)
      bf[nt] = *(const f16x8*)(base + boff + nt * 1024 + cx0);
    if (st) {
#pragma unroll
      for (int i = 0; i < 4; ++i)
        g2l16(Aq + (size_t)(i * 64 + srow) * C_ + c1g + scol,
              sh.ring + nxOff + i * 4096 + t * 8);
    }
    __builtin_amdgcn_s_setprio(1);
#pragma unroll
    for (int mt = 0; mt < 4; ++mt)
#pragma unroll
      for (int nt = 0; nt < 8; ++nt)
        acc[mt][nt] = mfma16(af[mt], bf[nt], acc[mt][nt]);
    __builtin_amdgcn_s_setprio(0);

    // ---- phase kk=1 ----
#pragma unroll
    for (int mt = 0; mt < 4; ++mt)
      af[mt] = *(const f16x8*)(base + aoff + mt * 1024 + cx1);
#pragma unroll
    for (int nt = 0; nt < 8; ++nt)
      bf[nt] = *(const f16x8*)(base + boff + nt * 1024 + cx1);
    if (st) {
#pragma unroll
      for (int i = 0; i < 4; ++i)
        g2l16(Bk + (size_t)(i * 64 + srow) * C_ + c1g + scol,
              sh.ring + nxOff + 16384 + i * 4096 + t * 8);
    }
    __builtin_amdgcn_s_setprio(1);
#pragma unroll
    for (int mt = 0; mt < 4; ++mt)
#pragma unroll
      for (int nt = 0; nt < 8; ++nt)
        acc[mt][nt] = mfma16(af[mt], bf[nt], acc[mt][nt]);
    __builtin_amdgcn_s_setprio(0);

    asm volatile("s_waitcnt vmcnt(0)" ::: "memory");
    __builtin_amdgcn_s_barrier();
    cur ^= 1;
  }

  // ---- tile row max (merge wx halves through sred) ----
#pragma unroll
  for (int mt = 0; mt < 4; ++mt)
#pragma unroll
    for (int r = 0; r < 4; ++r) {
      float v = -1e30f;
#pragma unroll
      for (int nt = 0; nt < 8; ++nt) v = fmaxf(v, acc[mt][nt][r]);
#pragma unroll
      for (int msk = 1; msk < 16; msk <<= 1) v = fmaxf(v, __shfl_xor(v, msk));
      if (lq == 0) sred[wx][wy * 64 + mt * 16 + quad * 4 + r] = v;
    }
  __syncthreads();
  float mrow[4][4];
#pragma unroll
  for (int mt = 0; mt < 4; ++mt)
#pragma unroll
    for (int r = 0; r < 4; ++r) {
      int rr = wy * 64 + mt * 16 + quad * 4 + r;
      mrow[mt][r] = fmaxf(sred[0][rr], sred[1][rr]);
    }

  // ---- E = exp(s - m_t): XOR-swizzled ebuf transpose -> 16B stores ----
  float rsum[4][4];
#pragma unroll
  for (int mt = 0; mt < 4; ++mt)
#pragma unroll
    for (int r = 0; r < 4; ++r) rsum[mt][r] = 0.f;

#pragma unroll
  for (int mt = 0; mt < 4; ++mt) {
    __syncthreads();  // prev phase's ebuf reads done (mt=0: K-loop/sred done)
#pragma unroll
    for (int nt = 0; nt < 8; ++nt) {
      f32x4 v = acc[mt][nt];
      // chunk = col>>3; swizzled chunk = chunk ^ (quad<<1)
      int cs = ((wx * 16 + nt * 2 + (lq >> 3)) ^ (quad << 1)) * 8 + (lq & 7);
#pragma unroll
      for (int r = 0; r < 4; ++r) {
        float e = __expf(v[r] - mrow[mt][r]);
        rsum[mt][r] += e;
        sh.ebuf[(wy * 16 + quad * 4 + r) * 272 + cs] = (f16)e;
      }
    }
    __syncthreads();  // ebuf visible
#pragma unroll
    for (int i = 0; i < 4; ++i) {
      int idx = i * 512 + t;
      int rl = idx >> 5, ck = idx & 31;
      int cr = (ck ^ (((rl >> 2) & 3) << 1)) * 8;
      f16x8 v8 = *(const f16x8*)(sh.ebuf + rl * 272 + cr);
      int grow = (rl >> 4) * 64 + mt * 16 + (rl & 15);
      *(f16x8*)(Eb + (size_t)grow * HW_ + ck * 8) = v8;
    }
  }

  // ---- row-sum partials -> mlpart ----
#pragma unroll
  for (int mt = 0; mt < 4; ++mt)
#pragma unroll
    for (int r = 0; r < 4; ++r) {
      float v = rsum[mt][r];
#pragma unroll
      for (int msk = 1; msk < 16; msk <<= 1) v += __shfl_xor(v, msk);
      if (lq == 0) sred[wx][wy * 64 + mt * 16 + quad * 4 + r] = v;
    }
  __syncthreads();
  if (wx == 0 && lq == 0) {
#pragma unroll
    for (int mt = 0; mt < 4; ++mt)
#pragma unroll
      for (int r = 0; r < 4; ++r) {
        int rr = wy * 64 + mt * 16 + quad * 4 + r;
        mlb[(size_t)rr * 16] = make_float2(mrow[mt][r], sred[0][rr] + sred[1][rr]);
      }
  }
}

// ---- pass 3: exact softmax merge -> alpha[row][kt16] = exp(m_t-m)/l ------
__global__ __launch_bounds__(256) void k_red(const float2* __restrict__ mlpart,
                                             float* __restrict__ alpha) {
  int row = blockIdx.x * 256 + threadIdx.x;
  const float2* p = mlpart + (size_t)row * 16;
  float2 loc[16];
  float m = -1e30f;
#pragma unroll
  for (int i = 0; i < 16; ++i) {
    loc[i] = p[i];
    m = fmaxf(m, loc[i].x);
  }
  float l = 0.f;
#pragma unroll
  for (int i = 0; i < 16; ++i) l += loc[i].y * __expf(loc[i].x - m);
  float invl = 1.f / l;
#pragma unroll
  for (int i = 0; i < 16; ++i)
    alpha[(size_t)row * 16 + i] = __expf(loc[i].x - m) * invl;
}

// ------ pass 4: (E*alpha) x V — R13 ring-3 structure, waits stripped -----
// 256q x 128ch, 8 waves, BK=64, 64 slots, ring-3, vmcnt(6) boundary.
#define PV_STAGE_A(i)                                                         \
  g2l16(Ap + (size_t)((i)*64 + srow) * HW_ + s2 * 64 + scol,                  \
        sm + pnOff + (i)*4096 + t * 8)
#define PV_STAGE_B(i)                                                         \
  g2l16(Bv + (size_t)((i)*64 + srow) * HW_ + s2 * 64 + scol,                  \
        sm + pnOff + 16384 + (i)*4096 + t * 8)

#define PV_PHASE(CX, STAGE_STMT, POST_STMT)                                   \
  {                                                                           \
    f16x8 af0 = *(const f16x8*)(As_s + aoff + 0 * 1024 + (CX));               \
    f16x8 af1 = *(const f16x8*)(As_s + aoff + 1 * 1024 + (CX));               \
    f16x8 af2 = *(const f16x8*)(As_s + aoff + 2 * 1024 + (CX));               \
    f16x8 af3 = *(const f16x8*)(As_s + aoff + 3 * 1024 + (CX));               \
    f16x8 bf0 = *(const f16x8*)(Bs_s + boff + 0 * 1024 + (CX));               \
    f16x8 bf1 = *(const f16x8*)(Bs_s + boff + 1 * 1024 + (CX));               \
    f16x8 bf2 = *(const f16x8*)(Bs_s + boff + 2 * 1024 + (CX));               \
    f16x8 bf3 = *(const f16x8*)(Bs_s + boff + 3 * 1024 + (CX));               \
    STAGE_STMT;                                                               \
    __builtin_amdgcn_s_setprio(1);                                            \
    af0 *= aal[0]; af1 *= aal[1]; af2 *= aal[2]; af3 *= aal[3];               \
    f16x8 q0 = bf0 * bf0, q1 = bf1 * bf1, q2 = bf2 * bf2, q3 = bf3 * bf3;     \
    accM [0][0] = mfma16(af0, bf0, accM [0][0]);                              \
    accM2[0][0] = mfma16(af0, q0,  accM2[0][0]);                              \
    accM [0][1] = mfma16(af0, bf1, accM [0][1]);                              \
    accM2[0][1] = mfma16(af0, q1,  accM2[0][1]);                              \
    accM [0][2] = mfma16(af0, bf2, accM [0][2]);                              \
    accM2[0][2] = mfma16(af0, q2,  accM2[0][2]);                              \
    accM [0][3] = mfma16(af0, bf3, accM [0][3]);                              \
    accM2[0][3] = mfma16(af0, q3,  accM2[0][3]);                              \
    accM [1][0] = mfma16(af1, bf0, accM [1][0]);                              \
    accM2[1][0] = mfma16(af1, q0,  accM2[1][0]);                              \
    accM [1][1] = mfma16(af1, bf1, accM [1][1]);                              \
    accM2[1][1] = mfma16(af1, q1,  accM2[1][1]);                              \
    accM [1][2] = mfma16(af1, bf2, accM [1][2]);                              \
    accM2[1][2] = mfma16(af1, q2,  accM2[1][2]);                              \
    accM [1][3] = mfma16(af1, bf3, accM [1][3]);                              \
    accM2[1][3] = mfma16(af1, q3,  accM2[1][3]);                              \
    accM [2][0] = mfma16(af2, bf0, accM [2][0]);                              \
    accM2[2][0] = mfma16(af2, q0,  accM2[2][0]);                              \
    accM [2][1] = mfma16(af2, bf1, accM [2][1]);                              \
    accM2[2][1] = mfma16(af2, q1,  accM2[2][1]);                              \
    accM [2][2] = mfma16(af2, bf2, accM [2][2]);                              \
    accM2[2][2] = mfma16(af2, q2,  accM2[2][2]);                              \
    accM [2][3] = mfma16(af2, bf3, accM [2][3]);                              \
    accM2[2][3] = mfma16(af2, q3,  accM2[2][3]);                              \
    accM [3][0] = mfma16(af3, bf0, accM [3][0]);                              \
    accM2[3][0] = mfma16(af3, q0,  accM2[3][0]);                              \
    accM [3][1] = mfma16(af3, bf1, accM [3][1]);                              \
    accM2[3][1] = mfma16(af3, q1,  accM2[3][1]);                              \
    accM [3][2] = mfma16(af3, bf2, accM [3][2]);                              \
    accM2[3][2] = mfma16(af3, q2,  accM2[3][2]);                              \
    accM [3][3] = mfma16(af3, bf3, accM [3][3]);                              \
    accM2[3][3] = mfma16(af3, q3,  accM2[3][3]);                              \
    __builtin_amdgcn_s_setprio(0);                                            \
    POST_STMT;                                                                \
  }

__global__ __launch_bounds__(512, 2) void k_pv(
    const f16* __restrict__ P, const float* __restrict__ alphaG,
    const f16* __restrict__ V, const float* __restrict__ cx,
    const float2* __restrict__ cxs, float* __restrict__ out,
    int qspan, int qbase, int qt256) {
  int npairs = (int)gridDim.x >> 2;
  int id = blockIdx.x, pair, ct;
  if ((npairs & 7) == 0) {
    int x = id & 7, j = id >> 3, ppx = npairs >> 3;
    pair = x * ppx + (j >> 2);
    ct = j & 3;
  } else {
    pair = id >> 2;
    ct = id & 3;
  }
  int bz = pair / qt256, qt = pair - bz * qt256;

  const f16* Ap = P + ((size_t)(bz * qspan + qt * 256)) * HW_;
  const f16* Bv = V + ((size_t)(bz * C_ + ct * 128)) * HW_;

  // LDS: 3 slots x (A 256x64 + B 128x64 f16 = 24576 f16) + alpha f16[256][17]
  __shared__ __align__(16) f16 sm[3 * 24576 + 256 * 17];
  f16* Alh = sm + 3 * 24576;

  int t = threadIdx.x, wave = t >> 6, lane = t & 63, lq = lane & 15, quad = lane >> 4;
  int wy = wave >> 1, wx = wave & 1;

  // ---- stage alpha as f16 (cast f32->f16 at use in baseline: identical) --
  {
    const float* ag = alphaG + ((size_t)(bz * qspan + qt * 256)) * 16;
#pragma unroll
    for (int i = 0; i < 8; ++i) {
      int e = i * 512 + t;
      Alh[(e >> 4) * 17 + (e & 15)] = (f16)ag[e];
    }
  }

  // staging map: thread t covers (row = t>>3 within 64-row chunk, 16B chunk)
  int srow = t >> 3;
  int scol = ((t & 7) ^ (srow & 7)) * 8;  // pre-swizzled source col (f16)

  // fragment read offsets (f16 units, within slot)
  int aoff = (wy * 64 + lq) * 64;
  int boff = (wx * 64 + lq) * 64;
  int cx0 = (quad * 8) ^ ((lq & 7) << 3);        // kk=0, swizzled
  int cx1 = (32 + quad * 8) ^ ((lq & 7) << 3);   // kk=1, swizzled

  f32x4 accM[4][4], accM2[4][4];
#pragma unroll
  for (int mt = 0; mt < 4; ++mt)
#pragma unroll
    for (int nt = 0; nt < 4; ++nt) {
      accM[mt][nt] = (f32x4){0, 0, 0, 0};
      accM2[mt][nt] = (f32x4){0, 0, 0, 0};
    }

  // ---- prologue: stage slots 0,1 (6 loads each) ----
#pragma unroll
  for (int s0 = 0; s0 < 2; ++s0) {
    int off = s0 * 24576;
#pragma unroll
    for (int i = 0; i < 4; ++i)
      g2l16(Ap + (size_t)(i * 64 + srow) * HW_ + s0 * 64 + scol,
            sm + off + i * 4096 + t * 8);
#pragma unroll
    for (int i = 0; i < 2; ++i)
      g2l16(Bv + (size_t)(i * 64 + srow) * HW_ + s0 * 64 + scol,
            sm + off + 16384 + i * 4096 + t * 8);
  }
  asm volatile("s_waitcnt lgkmcnt(0)" ::: "memory");  // alpha ds_writes drained
  asm volatile("s_waitcnt vmcnt(6)" ::: "memory");    // slot 0 landed
  __builtin_amdgcn_s_barrier();

  // ---- main loop: 64 slots, ring-3, one barrier per slot ----
  int ph = 0, pn = 2;
  for (int s = 0; s < 64; ++s) {
    const f16* As_s = sm + ph * 24576;
    const f16* Bs_s = As_s + 16384;
    int pnOff = pn * 24576;
    int s2 = s + 2;
    bool st = s < 62;
    int ktl = s >> 2;  // 256-key alpha tile index
    f16 aal[4];
    aal[0] = Alh[(wy * 64 + lq +  0) * 17 + ktl];
    aal[1] = Alh[(wy * 64 + lq + 16) * 17 + ktl];
    aal[2] = Alh[(wy * 64 + lq + 32) * 17 + ktl];
    aal[3] = Alh[(wy * 64 + lq + 48) * 17 + ktl];

    PV_PHASE(cx0,
             if (st) { PV_STAGE_A(0); PV_STAGE_A(1); PV_STAGE_A(2); }, )
    PV_PHASE(cx1,
             if (st) { PV_STAGE_A(3); PV_STAGE_B(0); PV_STAGE_B(1); },
             if (st) { asm volatile("s_waitcnt vmcnt(6)" ::: "memory"); }
             else    { asm volatile("s_waitcnt vmcnt(0)" ::: "memory"); })
    __builtin_amdgcn_s_barrier();

    ph = (ph == 2) ? 0 : ph + 1;
    pn = (pn == 2) ? 0 : pn + 1;
  }

  // ---- epilogue: fused sqrt(clip(M2-M^2))*IN(c_x)+M, all lanes ----
  int chbase = ct * 128 + wx * 64;
#pragma unroll
  for (int mt = 0; mt < 4; ++mt) {
    int q0 = qbase + qt * 256 + wy * 64 + mt * 16 + quad * 4;
#pragma unroll
    for (int nt = 0; nt < 4; ++nt) {
      int c = chbase + nt * 16 + lq;
      float2 stc = cxs[bz * C_ + c];
      size_t base = ((size_t)bz * C_ + c) * HW_ + q0;
      float4 cv = *(const float4*)(cx + base);
      f32x4 m1 = accM[mt][nt], m2 = accM2[mt][nt];
      float4 o;
      o.x = sqrtf(fmaxf(m2[0] - m1[0] * m1[0], 1e-6f)) * ((cv.x - stc.x) * stc.y) + m1[0];
      o.y = sqrtf(fmaxf(m2[1] - m1[1] * m1[1], 1e-6f)) * ((cv.y - stc.x) * stc.y) + m1[1];
      o.z = sqrtf(fmaxf(m2[2] - m1[2] * m1[2], 1e-6f)) * ((cv.z - stc.x) * stc.y) + m1[2];
      o.w = sqrtf(fmaxf(m2[3] - m1[3] * m1[3], 1e-6f)) * ((cv.w - stc.x) * stc.y) + m1[3];
      *(float4*)(out + base) = o;
    }
  }
}

// --------------------------------- host -----------------------------------
extern "C" void kernel_launch(void* const* d_in, const int* in_sizes, int n_in,
                              void* d_out, int out_size, void* d_ws,
                              size_t ws_size, hipStream_t stream) {
  const float* c_x = (const float*)d_in[0];
  const float* s_x = (const float*)d_in[1];
  const float* c1x = (const float*)d_in[2];
  const float* s1x = (const float*)d_in[3];
  float* out = (float*)d_out;

  char* ws = (char*)d_ws;
  size_t o = 0;
  f16* Qt = (f16*)(ws + o);  o += (size_t)B_ * HW_ * C_ * 2;        // 16 MiB
  f16* Kt = (f16*)(ws + o);  o += (size_t)B_ * HW_ * C_ * 2;        // 16 MiB
  f16* Vh = (f16*)(ws + o);  o += (size_t)B_ * HW_ * C_ * 2;        // 16 MiB
  float2* cxs = (float2*)(ws + o); o += B_ * C_ * sizeof(float2);
  float2* c1s = (float2*)(ws + o); o += B_ * C_ * sizeof(float2);
  float2* s1s = (float2*)(ws + o); o += B_ * C_ * sizeof(float2);
  size_t fixed = (o + 255) & ~(size_t)255;

  // score-region tiers: rows = nb*qspan; bytes/row = E + mlpart + alpha(f32)
  const size_t per_row = (size_t)HW_ * 2 + 16 * 8 + 16 * 4;
  struct Cfg { int nb, qs; };
  const Cfg cfgs[5] = {{4, 4096}, {1, 4096}, {1, 2048}, {1, 1024}, {1, 512}};
  Cfg cfg = cfgs[4];
  for (int i = 0; i < 5; ++i) {
    size_t rows = (size_t)cfgs[i].nb * cfgs[i].qs;
    if (fixed + rows * per_row <= ws_size) { cfg = cfgs[i]; break; }
  }
  const int nb = cfg.nb, qspan = cfg.qs, qt256 = qspan / 256;
  const int npair256 = nb * qt256;
  const size_t rows = (size_t)nb * qspan;
  f16* E = (f16*)(ws + fixed);
  float2* mlpart = (float2*)(ws + fixed + rows * HW_ * 2);
  float* alpha = (float*)(ws + fixed + rows * HW_ * 2 + rows * 16 * 8);

  k_stats<<<dim3(C_, B_, 3), 256, 0, stream>>>(c_x, c1x, s1x, cxs, c1s, s1s);
  k_prept<<<dim3(HW_ / 64, C_ / 64, B_), 256, 0, stream>>>(c1x, c1s, Qt);
  k_prept<<<dim3(HW_ / 64, C_ / 64, B_), 256, 0, stream>>>(s1x, s1s, Kt);
  k_prepv<<<dim3(B_ * C_ * HW_ / 8 / 256), 256, 0, stream>>>(s_x, Vh);

  for (int b0 = 0; b0 < B_; b0 += nb) {
    for (int qb = 0; qb < HW_; qb += qspan) {
      const f16* Qtp = Qt + ((size_t)b0 * HW_ + qb) * C_;
      const f16* Ktp = Kt + (size_t)b0 * HW_ * C_;
      const f16* Vp = Vh + (size_t)b0 * C_ * HW_;
      const float* cxp = c_x + (size_t)b0 * C_ * HW_;
      const float2* cxsp = cxs + b0 * C_;
      float* outp = out + (size_t)b0 * C_ * HW_;

      k_qk<<<dim3((unsigned)(npair256 * 16)), 512, 0, stream>>>(
          Qtp, Ktp, E, mlpart, qspan, qt256, npair256);
      k_red<<<dim3((unsigned)(rows / 256)), 256, 0, stream>>>(mlpart, alpha);
      k_pv<<<dim3((unsigned)(npair256 * 4)), 512, 0, stream>>>(
          E, alpha, Vp, cxp, cxsp, outp, qspan, qb, qt256);
    }
  }
}